// Round 1
// 139.389 us; speedup vs baseline: 1.0552x; 1.0552x over previous
//
#include <hip/hip_runtime.h>
#include <hip/hip_bf16.h>

// Shapes: x(8,16,4,64,64) f32, W(256,16,5,5) f32, b(1,1,8,32) f32
// out(8,32,8,64,64) f32.
//
// Reference reshapes (verified passing R1/R3):
//   conv input  t2[n,a,h,w] = x[b0, fl&15, ci, fl>>10, (fl>>4)&63],
//     fl = a*4096 + h*64 + w, n = ci*8 + b0
//   votes flat (n,oc,y,x) reinterpreted by routing as (bv,civ,h,w,o,ao)
//     with n = bv*4 + civ.
// Conv = implicit GEMM on v_mfma_f32_16x16x32_f16 (measured layouts m89/m120).

typedef _Float16 half8 __attribute__((ext_vector_type(8)));
typedef _Float16 half4v __attribute__((ext_vector_type(4)));
typedef float floatx4 __attribute__((ext_vector_type(4)));

#define EPSF 1e-7f

// ---------- cross-lane reductions at VALU rate (no ds_bpermute/swizzle) ----------
template <int CTRL>
__device__ __forceinline__ float dppmov(float x) {
  return __int_as_float(__builtin_amdgcn_update_dpp(
      0, __float_as_int(x), CTRL, 0xf, 0xf, false));
}
// reduce-add over lane bits 0..2 (atoms): ^1, ^2, then ^7 half-mirror completes 8-group.
// Same butterfly values as xor1/xor2/xor4 (after xor1+xor2 every lane holds its
// 4-group sum, and the ^7 partner holds the adjacent 4-group sum).
__device__ __forceinline__ float red_a_add(float x) {
  x += dppmov<0xB1>(x);   // quad_perm [1,0,3,2] : ^1
  x += dppmov<0x4E>(x);   // quad_perm [2,3,0,1] : ^2
  x += dppmov<0x141>(x);  // row_half_mirror     : ^7
  return x;
}
// reduce over lane bits 3..5 (capsule o): ^8 = row_ror:8 (within 16-row),
// ^16/^32 = gfx950 permlane swaps (self-swap: a OP b gives the butterfly).
__device__ __forceinline__ float red_o_add(float x) {
  x += dppmov<0x128>(x);  // row_ror:8 == ^8
  { float a = x, b = x;
    asm("v_permlane16_swap_b32 %0, %1" : "+v"(a), "+v"(b));
    x = a + b; }
  { float a = x, b = x;
    asm("v_permlane32_swap_b32 %0, %1" : "+v"(a), "+v"(b));
    x = a + b; }
  return x;
}
__device__ __forceinline__ float red_o_max(float x) {
  x = fmaxf(x, dppmov<0x128>(x));
  { float a = x, b = x;
    asm("v_permlane16_swap_b32 %0, %1" : "+v"(a), "+v"(b));
    x = fmaxf(a, b); }
  { float a = x, b = x;
    asm("v_permlane32_swap_b32 %0, %1" : "+v"(a), "+v"(b));
    x = fmaxf(a, b); }
  return x;
}

// LDS-tile transpose pack: x -> th (n, a0h, h, w, 8a) f16.  (unchanged)
__global__ __launch_bounds__(256) void k_pack2(const float* __restrict__ x,
                                               _Float16* __restrict__ th) {
  __shared__ float lin[32 * 306 + 18];
  const int bid = blockIdx.x;            // 256 blocks
  const int n   = bid >> 3;
  const int a0h = (bid >> 2) & 1;
  const int W0  = (bid & 3) * 16;
  const int ci = n >> 3, b0 = n & 7;
  const int tid = threadIdx.x;
  const float* xb = x + b0 * 262144 + ci * 4096 + W0;

  for (int p = 0; p < 8; ++p) {
    int rr = p * 64 + (tid >> 2);
    int q  = (tid & 3) * 4;
    int a1 = rr >> 5, m = rr & 31;
    float4 v = *(const float4*)(xb + a1 * 16384 + (a0h * 32 + m) * 64 + q);
    float* d = lin + m * 306 + a1 * 18 + q;
    d[0] = v.x; d[1] = v.y; d[2] = v.z; d[3] = v.w;
  }
  __syncthreads();

  _Float16* tb = th + (size_t)n * 65536 + a0h * 32768 + W0 * 128;
  for (int hh = 0; hh < 4; ++hh) {
    int w1 = tid >> 4, a1 = tid & 15;
    half8 v;
#pragma unroll
    for (int j = 0; j < 8; ++j)
      v[j] = (_Float16)lin[(j * 4 + hh) * 306 + a1 * 18 + w1];
    *(half8*)(tb + hh * 8192 + w1 * 128 + a1 * 8) = v;
  }
}

// W (oc,a,ky,kx) f32 -> Wp (kk=0..25, oc, a) f16; plane kk==25 is zeros. (unchanged)
__global__ __launch_bounds__(256) void k_packw(const float* __restrict__ W,
                                               _Float16* __restrict__ Wp) {
  int id = blockIdx.x * 256 + threadIdx.x;      // 106,496 = 26*4096
  int a  = id & 15;
  int oc = (id >> 4) & 255;
  int kk = id >> 12;
  Wp[id] = (kk < 25) ? (_Float16)W[oc * 400 + a * 25 + kk] : (_Float16)0.0f;
}

// One block per (n,y): M=256 oc x N=64 px, K=400. Main loop unchanged (R3-passing);
// epilogue now stages the 32KB output tile in LDS (bank-swizzled) and writes
// coalesced half8 (128B segments) instead of 64 scalar 2B stores per thread.
__global__ __launch_bounds__(256) void k_conv(const _Float16* __restrict__ th,
                                              const _Float16* __restrict__ Wp,
                                              _Float16* __restrict__ votes) {
  __shared__ _Float16 lds[16384];   // tile uses [0,5440); epilogue reuses all 32KB
  const int y = blockIdx.x;
  const int n = blockIdx.y;
  const int tid = threadIdx.x;

  for (int c = tid; c < 680; c += 256) {
    int a0h = c / 340;
    int rem = c - a0h * 340;
    int r   = rem / 68;
    int col = rem - r * 68;
    int row = y + r - 2;
    half8 v = {};
    if (col >= 2 && col <= 65 && row >= 0 && row < 64)
      v = *(const half8*)(th + (size_t)(((n * 2 + a0h) * 64 + row) * 64 + (col - 2)) * 8);
    *(half8*)(lds + c * 8) = v;
  }
  __syncthreads();

  const int lane  = tid & 63;
  const int wv    = tid >> 6;
  const int col16 = lane & 15;
  const int quad  = lane >> 4;      // 0..3
  const int t     = quad >> 1;      // tap-within-pair
  const int a0h   = quad & 1;       // atom-half
  const int m0    = wv * 64;

  floatx4 acc[4][4] = {};

  const _Float16* wbase = Wp + (size_t)t * 4096 + (m0 + col16) * 16 + a0h * 8;
  half8 af[4], an[4], bf[4];
#pragma unroll
  for (int oct = 0; oct < 4; ++oct)
    af[oct] = *(const half8*)(wbase + oct * 256);

  for (int s = 0; s < 13; ++s) {
    int kkb = 2 * s + t; if (kkb > 24) kkb = 24;   // clamp -> zero plane 25
    int ky = kkb / 5;
    int kx = kkb - ky * 5;
    const _Float16* lb = lds + (a0h * 340 + ky * 68 + col16 + kx) * 8;
#pragma unroll
    for (int xt = 0; xt < 4; ++xt)
      bf[xt] = *(const half8*)(lb + xt * 128);
    int sn = (s + 1 < 13) ? (s + 1) : s;
#pragma unroll
    for (int oct = 0; oct < 4; ++oct)
      an[oct] = *(const half8*)(wbase + (size_t)sn * 8192 + oct * 256);
#pragma unroll
    for (int oct = 0; oct < 4; ++oct)
#pragma unroll
      for (int xt = 0; xt < 4; ++xt)
        acc[oct][xt] = __builtin_amdgcn_mfma_f32_16x16x32_f16(
            af[oct], bf[xt], acc[oct][xt], 0, 0, 0);
#pragma unroll
    for (int oct = 0; oct < 4; ++oct) af[oct] = an[oct];
  }

  // ---- epilogue: LDS stage (swizzled: xx ^ (((oc&15)>>1)<<3)) + half8 writeout ----
  __syncthreads();   // other waves may still read the input tile region
#pragma unroll
  for (int oct = 0; oct < 4; ++oct)
#pragma unroll
    for (int xt = 0; xt < 4; ++xt)
#pragma unroll
      for (int r = 0; r < 4; ++r) {
        int oc = m0 + oct * 16 + quad * 4 + r;
        int xx = xt * 16 + col16;
        int sw = (oc & 15) >> 1;
        lds[oc * 64 + (xx ^ (sw << 3))] = (_Float16)acc[oct][xt][r];
      }
  __syncthreads();
  _Float16* vb2 = votes + (size_t)n * 1048576 + y * 64;
#pragma unroll
  for (int it = 0; it < 8; ++it) {
    int idx = it * 256 + tid;          // 2048 half8 chunks
    int oc  = idx >> 3;
    int x0  = (idx & 7) << 3;
    int sw  = (oc & 15) >> 1;
    half8 hv = *(const half8*)(lds + oc * 64 + (x0 ^ (sw << 3)));
    *(half8*)(vb2 + (size_t)oc * 4096 + x0) = hv;
  }
}

// Routing v3: same math/decomposition as v2, but all cross-lane reductions via
// DPP/permlane (VALU rate, no ds ops), round-0 softmax folded to exact 1/8, and
// the so[] staging column XOR-swizzled (write bank = 4o + (wl^(a0>>2)) -> 2-way).
__global__ __launch_bounds__(256) void k_routing3(
    const _Float16* __restrict__ votes, const float* __restrict__ bias,
    float* __restrict__ out) {
  __shared__ float so[256 * 36];        // 36 KB
  const int tid  = threadIdx.x;
  const int lane = tid & 63;
  const int wv   = tid >> 6;
  const int bid  = blockIdx.x;          // 1024
  const int bv = bid >> 7;
  const int h  = (bid >> 1) & 63;
  const int W0 = (bid & 1) * 32;

  float4 bia = *(const float4*)(bias + lane * 4);
  const int o     = lane >> 3;
  const int a0    = (lane & 7) * 4;
  const int shift = a0 >> 2;            // so[] column swizzle for this lane's rows
  float bb[4] = {bia.x, bia.y, bia.z, bia.w};

  for (int k = 0; k < 8; ++k) {
    const int wl = wv * 8 + k;          // 0..31
    const int w  = W0 + wl;
    const _Float16* vb = votes + (size_t)bv * 4194304 + h * 16384 + w * 256 + lane * 4;
    float v[4][4];
#pragma unroll
    for (int i = 0; i < 4; ++i) {
      half4v hv = *(const half4v*)(vb + (size_t)i * 1048576);
#pragma unroll
      for (int j = 0; j < 4; ++j) v[i][j] = (float)hv[j];
    }

    float logit[4], act[4], pr[4];

    // ---- round 0: logits==0 -> route==1/8 exactly; skip the softmax ----
#pragma unroll
    for (int j = 0; j < 4; ++j)
      pr[j] = fmaf(0.125f, (v[0][j] + v[1][j]) + (v[2][j] + v[3][j]), bb[j]);
    {
      float sq = pr[0]*pr[0] + pr[1]*pr[1] + pr[2]*pr[2] + pr[3]*pr[3];
      sq = red_a_add(sq);
      float sc = sq * __builtin_amdgcn_rcpf(1.f + sq)
                    * __builtin_amdgcn_rsqf(sq + EPSF);
#pragma unroll
      for (int j = 0; j < 4; ++j) act[j] = pr[j] * sc;
    }
#pragma unroll
    for (int i = 0; i < 4; ++i) {
      float ag = v[i][0]*act[0] + v[i][1]*act[1] + v[i][2]*act[2] + v[i][3]*act[3];
      logit[i] = red_a_add(ag);
    }

    // ---- rounds 1,2 ----
#pragma unroll
    for (int r = 1; r < 3; ++r) {
      float route[4];
#pragma unroll
      for (int i = 0; i < 4; ++i) {
        float m = red_o_max(logit[i]);
        float e = __expf(logit[i] - m);
        float s = red_o_add(e);
        route[i] = e * __builtin_amdgcn_rcpf(s);
      }
#pragma unroll
      for (int j = 0; j < 4; ++j) pr[j] = bb[j];
#pragma unroll
      for (int i = 0; i < 4; ++i)
#pragma unroll
        for (int j = 0; j < 4; ++j)
          pr[j] = fmaf(route[i], v[i][j], pr[j]);
      float sq = pr[0]*pr[0] + pr[1]*pr[1] + pr[2]*pr[2] + pr[3]*pr[3];
      sq = red_a_add(sq);
      float sc = sq * __builtin_amdgcn_rcpf(1.f + sq)
                    * __builtin_amdgcn_rsqf(sq + EPSF);
#pragma unroll
      for (int j = 0; j < 4; ++j) act[j] = pr[j] * sc;
      if (r < 2) {
#pragma unroll
        for (int i = 0; i < 4; ++i) {
          float ag = v[i][0]*act[0] + v[i][1]*act[1] + v[i][2]*act[2] + v[i][3]*act[3];
          logit[i] += red_a_add(ag);
        }
      }
    }

    // stage: row = (a0+j)*8 + o, col = wl ^ (row>>5)  (row>>5 == a0>>2)
#pragma unroll
    for (int j = 0; j < 4; ++j)
      so[((a0 + j) * 8 + o) * 36 + (wl ^ shift)] = act[j];
  }
  __syncthreads();

  // Coalesced writeout; de-swizzle is compile-time per unrolled p (p == r>>5):
  // col base = w0 ^ (p&4), vector components permuted by j ^ (p&3).
  float* ob = out + (size_t)bv * 1048576 + h * 64 + W0;
#pragma unroll
  for (int p = 0; p < 8; ++p) {
    int r  = p * 32 + (tid >> 3);
    int w0 = (tid & 7) * 4;
    float4 tv = *(const float4*)(so + r * 36 + (w0 ^ (p & 4)));
    float tt[4] = {tv.x, tv.y, tv.z, tv.w};
    const int pm = p & 3;
    float4 u = make_float4(tt[0 ^ pm], tt[1 ^ pm], tt[2 ^ pm], tt[3 ^ pm]);
    *(float4*)(ob + (size_t)r * 4096 + w0) = u;
  }
}

extern "C" void kernel_launch(void* const* d_in, const int* in_sizes, int n_in,
                              void* d_out, int out_size, void* d_ws, size_t ws_size,
                              hipStream_t stream) {
  const float* x  = (const float*)d_in[0];
  const float* W  = (const float*)d_in[1];
  const float* b  = (const float*)d_in[2];
  float* out = (float*)d_out;

  _Float16* th    = (_Float16*)d_ws;            // 2,097,152 halves (4 MB)
  _Float16* Wp    = th + 2097152;               // 106,496 halves (208 KB)
  _Float16* votes = Wp + 106496;                // 33,554,432 halves (64 MB)

  k_pack2<<<256, 256, 0, stream>>>(x, th);
  k_packw<<<416, 256, 0, stream>>>(W, Wp);
  k_conv<<<dim3(64, 32), 256, 0, stream>>>(th, Wp, votes);
  k_routing3<<<1024, 256, 0, stream>>>(votes, b, out);
}

// Round 2
// 137.878 us; speedup vs baseline: 1.0668x; 1.0110x over previous
//
#include <hip/hip_runtime.h>
#include <hip/hip_bf16.h>

// Shapes: x(8,16,4,64,64) f32, W(256,16,5,5) f32, b(1,1,8,32) f32
// out(8,32,8,64,64) f32.
//
// Reference reshapes (verified passing R1/R3):
//   conv input  t2[n,a,h,w] = x[b0, fl&15, ci, fl>>10, (fl>>4)&63],
//     fl = a*4096 + h*64 + w, n = ci*8 + b0
//   votes flat (n,oc,y,x) reinterpreted by routing as (bv,civ,h,w,o,ao)
//     with n = bv*4 + civ.
// Conv = implicit GEMM on v_mfma_f32_16x16x32_f16 (measured layouts m89/m120).

typedef _Float16 half8 __attribute__((ext_vector_type(8)));
typedef _Float16 half4v __attribute__((ext_vector_type(4)));
typedef float floatx4 __attribute__((ext_vector_type(4)));

#define EPSF 1e-7f

// ---------- cross-lane reductions at VALU rate (no ds_bpermute/swizzle) ----------
template <int CTRL>
__device__ __forceinline__ float dppmov(float x) {
  return __int_as_float(__builtin_amdgcn_update_dpp(
      0, __float_as_int(x), CTRL, 0xf, 0xf, false));
}
// reduce-add over lane bits 0..2 (atoms): ^1, ^2, then ^7 half-mirror completes 8-group.
__device__ __forceinline__ float red_a_add(float x) {
  x += dppmov<0xB1>(x);   // quad_perm [1,0,3,2] : ^1
  x += dppmov<0x4E>(x);   // quad_perm [2,3,0,1] : ^2
  x += dppmov<0x141>(x);  // row_half_mirror     : ^7
  return x;
}
// reduce over lane bits 3..5 (capsule o): ^8 = row_ror:8, ^16/^32 = permlane swaps.
__device__ __forceinline__ float red_o_add(float x) {
  x += dppmov<0x128>(x);  // row_ror:8 == ^8
  { float a = x, b = x;
    asm("v_permlane16_swap_b32 %0, %1" : "+v"(a), "+v"(b));
    x = a + b; }
  { float a = x, b = x;
    asm("v_permlane32_swap_b32 %0, %1" : "+v"(a), "+v"(b));
    x = a + b; }
  return x;
}
__device__ __forceinline__ float red_o_max(float x) {
  x = fmaxf(x, dppmov<0x128>(x));
  { float a = x, b = x;
    asm("v_permlane16_swap_b32 %0, %1" : "+v"(a), "+v"(b));
    x = fmaxf(a, b); }
  { float a = x, b = x;
    asm("v_permlane32_swap_b32 %0, %1" : "+v"(a), "+v"(b));
    x = fmaxf(a, b); }
  return x;
}

// LDS-tile transpose pack: x -> th (n, a0h, h, w, 8a) f16.  (unchanged)
__global__ __launch_bounds__(256) void k_pack2(const float* __restrict__ x,
                                               _Float16* __restrict__ th) {
  __shared__ float lin[32 * 306 + 18];
  const int bid = blockIdx.x;            // 256 blocks
  const int n   = bid >> 3;
  const int a0h = (bid >> 2) & 1;
  const int W0  = (bid & 3) * 16;
  const int ci = n >> 3, b0 = n & 7;
  const int tid = threadIdx.x;
  const float* xb = x + b0 * 262144 + ci * 4096 + W0;

  for (int p = 0; p < 8; ++p) {
    int rr = p * 64 + (tid >> 2);
    int q  = (tid & 3) * 4;
    int a1 = rr >> 5, m = rr & 31;
    float4 v = *(const float4*)(xb + a1 * 16384 + (a0h * 32 + m) * 64 + q);
    float* d = lin + m * 306 + a1 * 18 + q;
    d[0] = v.x; d[1] = v.y; d[2] = v.z; d[3] = v.w;
  }
  __syncthreads();

  _Float16* tb = th + (size_t)n * 65536 + a0h * 32768 + W0 * 128;
  for (int hh = 0; hh < 4; ++hh) {
    int w1 = tid >> 4, a1 = tid & 15;
    half8 v;
#pragma unroll
    for (int j = 0; j < 8; ++j)
      v[j] = (_Float16)lin[(j * 4 + hh) * 306 + a1 * 18 + w1];
    *(half8*)(tb + hh * 8192 + w1 * 128 + a1 * 8) = v;
  }
}

// W (oc,a,ky,kx) f32 -> Wp (kk=0..25, oc, a) f16; plane kk==25 is zeros. (unchanged)
__global__ __launch_bounds__(256) void k_packw(const float* __restrict__ W,
                                               _Float16* __restrict__ Wp) {
  int id = blockIdx.x * 256 + threadIdx.x;      // 106,496 = 26*4096
  int a  = id & 15;
  int oc = (id >> 4) & 255;
  int kk = id >> 12;
  Wp[id] = (kk < 25) ? (_Float16)W[oc * 400 + a * 25 + kk] : (_Float16)0.0f;
}

// One block per (n,y): M=256 oc x N=64 px, K=400.  (unchanged from R1)
__global__ __launch_bounds__(256) void k_conv(const _Float16* __restrict__ th,
                                              const _Float16* __restrict__ Wp,
                                              _Float16* __restrict__ votes) {
  __shared__ _Float16 lds[16384];   // tile uses [0,5440); epilogue reuses all 32KB
  const int y = blockIdx.x;
  const int n = blockIdx.y;
  const int tid = threadIdx.x;

  for (int c = tid; c < 680; c += 256) {
    int a0h = c / 340;
    int rem = c - a0h * 340;
    int r   = rem / 68;
    int col = rem - r * 68;
    int row = y + r - 2;
    half8 v = {};
    if (col >= 2 && col <= 65 && row >= 0 && row < 64)
      v = *(const half8*)(th + (size_t)(((n * 2 + a0h) * 64 + row) * 64 + (col - 2)) * 8);
    *(half8*)(lds + c * 8) = v;
  }
  __syncthreads();

  const int lane  = tid & 63;
  const int wv    = tid >> 6;
  const int col16 = lane & 15;
  const int quad  = lane >> 4;      // 0..3
  const int t     = quad >> 1;      // tap-within-pair
  const int a0h   = quad & 1;       // atom-half
  const int m0    = wv * 64;

  floatx4 acc[4][4] = {};

  const _Float16* wbase = Wp + (size_t)t * 4096 + (m0 + col16) * 16 + a0h * 8;
  half8 af[4], an[4], bf[4];
#pragma unroll
  for (int oct = 0; oct < 4; ++oct)
    af[oct] = *(const half8*)(wbase + oct * 256);

  for (int s = 0; s < 13; ++s) {
    int kkb = 2 * s + t; if (kkb > 24) kkb = 24;   // clamp -> zero plane 25
    int ky = kkb / 5;
    int kx = kkb - ky * 5;
    const _Float16* lb = lds + (a0h * 340 + ky * 68 + col16 + kx) * 8;
#pragma unroll
    for (int xt = 0; xt < 4; ++xt)
      bf[xt] = *(const half8*)(lb + xt * 128);
    int sn = (s + 1 < 13) ? (s + 1) : s;
#pragma unroll
    for (int oct = 0; oct < 4; ++oct)
      an[oct] = *(const half8*)(wbase + (size_t)sn * 8192 + oct * 256);
#pragma unroll
    for (int oct = 0; oct < 4; ++oct)
#pragma unroll
      for (int xt = 0; xt < 4; ++xt)
        acc[oct][xt] = __builtin_amdgcn_mfma_f32_16x16x32_f16(
            af[oct], bf[xt], acc[oct][xt], 0, 0, 0);
#pragma unroll
    for (int oct = 0; oct < 4; ++oct) af[oct] = an[oct];
  }

  // ---- epilogue: LDS stage (swizzled: xx ^ (((oc&15)>>1)<<3)) + half8 writeout ----
  __syncthreads();
#pragma unroll
  for (int oct = 0; oct < 4; ++oct)
#pragma unroll
    for (int xt = 0; xt < 4; ++xt)
#pragma unroll
      for (int r = 0; r < 4; ++r) {
        int oc = m0 + oct * 16 + quad * 4 + r;
        int xx = xt * 16 + col16;
        int sw = (oc & 15) >> 1;
        lds[oc * 64 + (xx ^ (sw << 3))] = (_Float16)acc[oct][xt][r];
      }
  __syncthreads();
  _Float16* vb2 = votes + (size_t)n * 1048576 + y * 64;
#pragma unroll
  for (int it = 0; it < 8; ++it) {
    int idx = it * 256 + tid;          // 2048 half8 chunks
    int oc  = idx >> 3;
    int x0  = (idx & 7) << 3;
    int sw  = (oc & 15) >> 1;
    half8 hv = *(const half8*)(lds + oc * 64 + (x0 ^ (sw << 3)));
    *(half8*)(vb2 + (size_t)oc * 4096 + x0) = hv;
  }
}

// Routing v4: same math as v3 (DPP/permlane reductions, round-0 folded to 1/8),
// but 2x the blocks: each block = (bv, h, 16 w's), 4 positions per wave.
// so[] = 256 rows x stride 20 = 20 KB -> 8 blocks/CU (32 waves/CU, 100% occ cap),
// doubling latency hiding for the serial per-position dependency chains.
// Staging write bank = o*20 (all mult-of-4) + (wl^(a0>>2)) -> exactly 2-way (free).
__global__ __launch_bounds__(256) void k_routing4(
    const _Float16* __restrict__ votes, const float* __restrict__ bias,
    float* __restrict__ out) {
  __shared__ float so[256 * 20];        // 20 KB
  const int tid  = threadIdx.x;
  const int lane = tid & 63;
  const int wv   = tid >> 6;
  const int bid  = blockIdx.x;          // 2048
  const int bv = bid >> 8;
  const int h  = (bid >> 2) & 63;
  const int W0 = (bid & 3) * 16;

  float4 bia = *(const float4*)(bias + lane * 4);
  const int o     = lane >> 3;
  const int a0    = (lane & 7) * 4;
  const int shift = a0 >> 2;            // so[] column swizzle for this lane's rows
  float bb[4] = {bia.x, bia.y, bia.z, bia.w};

  for (int k = 0; k < 4; ++k) {
    const int wl = wv * 4 + k;          // 0..15
    const int w  = W0 + wl;
    const _Float16* vb = votes + (size_t)bv * 4194304 + h * 16384 + w * 256 + lane * 4;
    float v[4][4];
#pragma unroll
    for (int i = 0; i < 4; ++i) {
      half4v hv = *(const half4v*)(vb + (size_t)i * 1048576);
#pragma unroll
      for (int j = 0; j < 4; ++j) v[i][j] = (float)hv[j];
    }

    float logit[4], act[4], pr[4];

    // ---- round 0: logits==0 -> route==1/8 exactly; skip the softmax ----
#pragma unroll
    for (int j = 0; j < 4; ++j)
      pr[j] = fmaf(0.125f, (v[0][j] + v[1][j]) + (v[2][j] + v[3][j]), bb[j]);
    {
      float sq = pr[0]*pr[0] + pr[1]*pr[1] + pr[2]*pr[2] + pr[3]*pr[3];
      sq = red_a_add(sq);
      float sc = sq * __builtin_amdgcn_rcpf(1.f + sq)
                    * __builtin_amdgcn_rsqf(sq + EPSF);
#pragma unroll
      for (int j = 0; j < 4; ++j) act[j] = pr[j] * sc;
    }
#pragma unroll
    for (int i = 0; i < 4; ++i) {
      float ag = v[i][0]*act[0] + v[i][1]*act[1] + v[i][2]*act[2] + v[i][3]*act[3];
      logit[i] = red_a_add(ag);
    }

    // ---- rounds 1,2 ----
#pragma unroll
    for (int r = 1; r < 3; ++r) {
      float route[4];
#pragma unroll
      for (int i = 0; i < 4; ++i) {
        float m = red_o_max(logit[i]);
        float e = __expf(logit[i] - m);
        float s = red_o_add(e);
        route[i] = e * __builtin_amdgcn_rcpf(s);
      }
#pragma unroll
      for (int j = 0; j < 4; ++j) pr[j] = bb[j];
#pragma unroll
      for (int i = 0; i < 4; ++i)
#pragma unroll
        for (int j = 0; j < 4; ++j)
          pr[j] = fmaf(route[i], v[i][j], pr[j]);
      float sq = pr[0]*pr[0] + pr[1]*pr[1] + pr[2]*pr[2] + pr[3]*pr[3];
      sq = red_a_add(sq);
      float sc = sq * __builtin_amdgcn_rcpf(1.f + sq)
                    * __builtin_amdgcn_rsqf(sq + EPSF);
#pragma unroll
      for (int j = 0; j < 4; ++j) act[j] = pr[j] * sc;
      if (r < 2) {
#pragma unroll
        for (int i = 0; i < 4; ++i) {
          float ag = v[i][0]*act[0] + v[i][1]*act[1] + v[i][2]*act[2] + v[i][3]*act[3];
          logit[i] += red_a_add(ag);
        }
      }
    }

    // stage: row = (a0+j)*8 + o, col = wl ^ (row>>5)  (row>>5 == a0>>2)
#pragma unroll
    for (int j = 0; j < 4; ++j)
      so[((a0 + j) * 8 + o) * 20 + (wl ^ shift)] = act[j];
  }
  __syncthreads();

  // Coalesced writeout: 256 rows x 16 floats; de-swizzle per (p, tid):
  // s = r>>5, float4 base = w0 ^ (s&4), component permute j ^ (s&3).
  float* ob = out + (size_t)bv * 1048576 + h * 64 + W0;
#pragma unroll
  for (int p = 0; p < 4; ++p) {
    int r  = p * 64 + (tid >> 2);
    int w0 = (tid & 3) * 4;
    int s  = r >> 5;
    float4 tv = *(const float4*)(so + r * 20 + (w0 ^ (s & 4)));
    float tt[4] = {tv.x, tv.y, tv.z, tv.w};
    const int pm = s & 3;
    float4 u = make_float4(tt[0 ^ pm], tt[1 ^ pm], tt[2 ^ pm], tt[3 ^ pm]);
    *(float4*)(ob + (size_t)r * 4096 + w0) = u;
  }
}

extern "C" void kernel_launch(void* const* d_in, const int* in_sizes, int n_in,
                              void* d_out, int out_size, void* d_ws, size_t ws_size,
                              hipStream_t stream) {
  const float* x  = (const float*)d_in[0];
  const float* W  = (const float*)d_in[1];
  const float* b  = (const float*)d_in[2];
  float* out = (float*)d_out;

  _Float16* th    = (_Float16*)d_ws;            // 2,097,152 halves (4 MB)
  _Float16* Wp    = th + 2097152;               // 106,496 halves (208 KB)
  _Float16* votes = Wp + 106496;                // 33,554,432 halves (64 MB)

  k_pack2<<<256, 256, 0, stream>>>(x, th);
  k_packw<<<416, 256, 0, stream>>>(W, Wp);
  k_conv<<<dim3(64, 32), 256, 0, stream>>>(th, Wp, votes);
  k_routing4<<<2048, 256, 0, stream>>>(votes, b, out);
}

// Round 4
// 135.854 us; speedup vs baseline: 1.0827x; 1.0149x over previous
//
#include <hip/hip_runtime.h>
#include <hip/hip_bf16.h>

// Shapes: x(8,16,4,64,64) f32, W(256,16,5,5) f32, b(1,1,8,32) f32
// out(8,32,8,64,64) f32.
//
// Reference reshapes (verified passing R1/R2):
//   conv input  t2[n,a,h,w] = x[b0, fl&15, ci, fl>>10, (fl>>4)&63],
//     fl = a*4096 + h*64 + w, n = ci*8 + b0
//   votes flat (n,oc,y,x) reinterpreted by routing as (bv,civ,h,w,o,ao)
//     with n = bv*4 + civ.
// Conv = implicit GEMM on v_mfma_f32_16x16x32_f16 (measured layouts m89/m120).

typedef _Float16 half8 __attribute__((ext_vector_type(8)));
typedef _Float16 half4v __attribute__((ext_vector_type(4)));
typedef float floatx4 __attribute__((ext_vector_type(4)));

#define EPSF 1e-7f

// ---------- cross-lane reductions at VALU rate (no ds_bpermute/swizzle) ----------
template <int CTRL>
__device__ __forceinline__ float dppmov(float x) {
  return __int_as_float(__builtin_amdgcn_update_dpp(
      0, __float_as_int(x), CTRL, 0xf, 0xf, false));
}
// reduce-add over lane bits 0..2 (atoms): ^1, ^2, then ^7 half-mirror completes 8-group.
__device__ __forceinline__ float red_a_add(float x) {
  x += dppmov<0xB1>(x);   // quad_perm [1,0,3,2] : ^1
  x += dppmov<0x4E>(x);   // quad_perm [2,3,0,1] : ^2
  x += dppmov<0x141>(x);  // row_half_mirror     : ^7
  return x;
}
// reduce over lane bits 3..5 (capsule o): ^8 = row_ror:8, ^16/^32 = permlane swaps.
__device__ __forceinline__ float red_o_add(float x) {
  x += dppmov<0x128>(x);  // row_ror:8 == ^8
  { float a = x, b = x;
    asm("v_permlane16_swap_b32 %0, %1" : "+v"(a), "+v"(b));
    x = a + b; }
  { float a = x, b = x;
    asm("v_permlane32_swap_b32 %0, %1" : "+v"(a), "+v"(b));
    x = a + b; }
  return x;
}
__device__ __forceinline__ float red_o_max(float x) {
  x = fmaxf(x, dppmov<0x128>(x));
  { float a = x, b = x;
    asm("v_permlane16_swap_b32 %0, %1" : "+v"(a), "+v"(b));
    x = fmaxf(a, b); }
  { float a = x, b = x;
    asm("v_permlane32_swap_b32 %0, %1" : "+v"(a), "+v"(b));
    x = fmaxf(a, b); }
  return x;
}

// LDS-tile transpose pack: x -> th (n, a0h, h, w, 8a) f16.  (unchanged)
__global__ __launch_bounds__(256) void k_pack2(const float* __restrict__ x,
                                               _Float16* __restrict__ th) {
  __shared__ float lin[32 * 306 + 18];
  const int bid = blockIdx.x;            // 256 blocks
  const int n   = bid >> 3;
  const int a0h = (bid >> 2) & 1;
  const int W0  = (bid & 3) * 16;
  const int ci = n >> 3, b0 = n & 7;
  const int tid = threadIdx.x;
  const float* xb = x + b0 * 262144 + ci * 4096 + W0;

  for (int p = 0; p < 8; ++p) {
    int rr = p * 64 + (tid >> 2);
    int q  = (tid & 3) * 4;
    int a1 = rr >> 5, m = rr & 31;
    float4 v = *(const float4*)(xb + a1 * 16384 + (a0h * 32 + m) * 64 + q);
    float* d = lin + m * 306 + a1 * 18 + q;
    d[0] = v.x; d[1] = v.y; d[2] = v.z; d[3] = v.w;
  }
  __syncthreads();

  _Float16* tb = th + (size_t)n * 65536 + a0h * 32768 + W0 * 128;
  for (int hh = 0; hh < 4; ++hh) {
    int w1 = tid >> 4, a1 = tid & 15;
    half8 v;
#pragma unroll
    for (int j = 0; j < 8; ++j)
      v[j] = (_Float16)lin[(j * 4 + hh) * 306 + a1 * 18 + w1];
    *(half8*)(tb + hh * 8192 + w1 * 128 + a1 * 8) = v;
  }
}

// W (oc,a,ky,kx) f32 -> Wp (kk=0..25, oc, a) f16; plane kk==25 is zeros. (unchanged)
__global__ __launch_bounds__(256) void k_packw(const float* __restrict__ W,
                                               _Float16* __restrict__ Wp) {
  int id = blockIdx.x * 256 + threadIdx.x;      // 106,496 = 26*4096
  int a  = id & 15;
  int oc = (id >> 4) & 255;
  int kk = id >> 12;
  Wp[id] = (kk < 25) ? (_Float16)W[oc * 400 + a * 25 + kk] : (_Float16)0.0f;
}

// Conv v4 (bisect arm): 512 threads = 8 waves, each wave 32 oc x 64 px
// (m0 = wv*32, acc[2][4]); full-unrolled compile-time tap table; XCD-bijective
// block remap. NO setprio, NO forced occupancy clamp, and the epilogue is
// R2's exact 32KB staged writeout (thread count adapted). Same per-oc
// accumulation order as R2 -> votes bit-identical.
__global__ __launch_bounds__(512) void k_conv(const _Float16* __restrict__ th,
                                              const _Float16* __restrict__ Wp,
                                              _Float16* __restrict__ votes) {
  __shared__ _Float16 lds[16384];   // input tile [0,5440); epilogue reuses 32KB
  const int orig = blockIdx.x;      // 2048
  const int lid  = (orig & 7) * 256 + (orig >> 3);   // bijective (2048 % 8 == 0)
  const int y = lid & 63;
  const int n = lid >> 6;
  const int tid = threadIdx.x;

  for (int c = tid; c < 680; c += 512) {
    int a0h = c / 340;
    int rem = c - a0h * 340;
    int r   = rem / 68;
    int col = rem - r * 68;
    int row = y + r - 2;
    half8 v = {};
    if (col >= 2 && col <= 65 && row >= 0 && row < 64)
      v = *(const half8*)(th + (size_t)(((n * 2 + a0h) * 64 + row) * 64 + (col - 2)) * 8);
    *(half8*)(lds + c * 8) = v;
  }
  __syncthreads();

  const int lane  = tid & 63;
  const int wv    = tid >> 6;       // 0..7
  const int col16 = lane & 15;
  const int quad  = lane >> 4;      // 0..3
  const int t     = quad >> 1;      // tap-within-pair
  const int a0h   = quad & 1;       // atom-half
  const int m0    = wv * 32;

  floatx4 acc[2][4] = {};

  const _Float16* wbase = Wp + (size_t)t * 4096 + (m0 + col16) * 16 + a0h * 8;
  const _Float16* lbase = lds + (a0h * 340 + col16) * 8;

#pragma unroll
  for (int s = 0; s < 13; ++s) {
    const int k0 = 2 * s;
    const int k1 = (2 * s + 1 > 24) ? 24 : 2 * s + 1;   // clamped: weights zero there
    const int e0 = (k0 / 5) * 68 + (k0 % 5);
    const int e1 = (k1 / 5) * 68 + (k1 % 5);
    const _Float16* lb = lbase + (t ? e1 : e0) * 8;
    half8 bf[4], aw[2];
#pragma unroll
    for (int xt = 0; xt < 4; ++xt)
      bf[xt] = *(const half8*)(lb + xt * 128);
#pragma unroll
    for (int oct = 0; oct < 2; ++oct)
      aw[oct] = *(const half8*)(wbase + (size_t)s * 8192 + oct * 256);
#pragma unroll
    for (int oct = 0; oct < 2; ++oct)
#pragma unroll
      for (int xt = 0; xt < 4; ++xt)
        acc[oct][xt] = __builtin_amdgcn_mfma_f32_16x16x32_f16(
            aw[oct], bf[xt], acc[oct][xt], 0, 0, 0);
  }

  // ---- epilogue: R2's exact staged writeout (swizzle sw=(oc&15)>>1) ----
  __syncthreads();
#pragma unroll
  for (int oct = 0; oct < 2; ++oct)
#pragma unroll
    for (int xt = 0; xt < 4; ++xt)
#pragma unroll
      for (int r = 0; r < 4; ++r) {
        int oc = m0 + oct * 16 + quad * 4 + r;
        int xx = xt * 16 + col16;
        int sw = (oc & 15) >> 1;
        lds[oc * 64 + (xx ^ (sw << 3))] = (_Float16)acc[oct][xt][r];
      }
  __syncthreads();
  _Float16* vb2 = votes + (size_t)n * 1048576 + y * 64;
#pragma unroll
  for (int it = 0; it < 4; ++it) {
    int idx = it * 512 + tid;          // 2048 half8 chunks
    int oc  = idx >> 3;
    int x0  = (idx & 7) << 3;
    int sw  = (oc & 15) >> 1;
    half8 hv = *(const half8*)(lds + oc * 64 + (x0 ^ (sw << 3)));
    *(half8*)(vb2 + (size_t)oc * 4096 + x0) = hv;
  }
}

// Routing v4: EXACT R2-passing version (max-subtract restored).
__global__ __launch_bounds__(256) void k_routing4(
    const _Float16* __restrict__ votes, const float* __restrict__ bias,
    float* __restrict__ out) {
  __shared__ float so[256 * 20];        // 20 KB
  const int tid  = threadIdx.x;
  const int lane = tid & 63;
  const int wv   = tid >> 6;
  const int bid  = blockIdx.x;          // 2048
  const int bv = bid >> 8;
  const int h  = (bid >> 2) & 63;
  const int W0 = (bid & 3) * 16;

  float4 bia = *(const float4*)(bias + lane * 4);
  const int o     = lane >> 3;
  const int a0    = (lane & 7) * 4;
  const int shift = a0 >> 2;            // so[] column swizzle for this lane's rows
  float bb[4] = {bia.x, bia.y, bia.z, bia.w};

  for (int k = 0; k < 4; ++k) {
    const int wl = wv * 4 + k;          // 0..15
    const int w  = W0 + wl;
    const _Float16* vb = votes + (size_t)bv * 4194304 + h * 16384 + w * 256 + lane * 4;
    float v[4][4];
#pragma unroll
    for (int i = 0; i < 4; ++i) {
      half4v hv = *(const half4v*)(vb + (size_t)i * 1048576);
#pragma unroll
      for (int j = 0; j < 4; ++j) v[i][j] = (float)hv[j];
    }

    float logit[4], act[4], pr[4];

    // ---- round 0: logits==0 -> route==1/8 exactly; skip the softmax ----
#pragma unroll
    for (int j = 0; j < 4; ++j)
      pr[j] = fmaf(0.125f, (v[0][j] + v[1][j]) + (v[2][j] + v[3][j]), bb[j]);
    {
      float sq = pr[0]*pr[0] + pr[1]*pr[1] + pr[2]*pr[2] + pr[3]*pr[3];
      sq = red_a_add(sq);
      float sc = sq * __builtin_amdgcn_rcpf(1.f + sq)
                    * __builtin_amdgcn_rsqf(sq + EPSF);
#pragma unroll
      for (int j = 0; j < 4; ++j) act[j] = pr[j] * sc;
    }
#pragma unroll
    for (int i = 0; i < 4; ++i) {
      float ag = v[i][0]*act[0] + v[i][1]*act[1] + v[i][2]*act[2] + v[i][3]*act[3];
      logit[i] = red_a_add(ag);
    }

    // ---- rounds 1,2 ----
#pragma unroll
    for (int r = 1; r < 3; ++r) {
      float route[4];
#pragma unroll
      for (int i = 0; i < 4; ++i) {
        float m = red_o_max(logit[i]);
        float e = __expf(logit[i] - m);
        float s = red_o_add(e);
        route[i] = e * __builtin_amdgcn_rcpf(s);
      }
#pragma unroll
      for (int j = 0; j < 4; ++j) pr[j] = bb[j];
#pragma unroll
      for (int i = 0; i < 4; ++i)
#pragma unroll
        for (int j = 0; j < 4; ++j)
          pr[j] = fmaf(route[i], v[i][j], pr[j]);
      float sq = pr[0]*pr[0] + pr[1]*pr[1] + pr[2]*pr[2] + pr[3]*pr[3];
      sq = red_a_add(sq);
      float sc = sq * __builtin_amdgcn_rcpf(1.f + sq)
                    * __builtin_amdgcn_rsqf(sq + EPSF);
#pragma unroll
      for (int j = 0; j < 4; ++j) act[j] = pr[j] * sc;
      if (r < 2) {
#pragma unroll
        for (int i = 0; i < 4; ++i) {
          float ag = v[i][0]*act[0] + v[i][1]*act[1] + v[i][2]*act[2] + v[i][3]*act[3];
          logit[i] += red_a_add(ag);
        }
      }
    }

    // stage: row = (a0+j)*8 + o, col = wl ^ (row>>5)  (row>>5 == a0>>2)
#pragma unroll
    for (int j = 0; j < 4; ++j)
      so[((a0 + j) * 8 + o) * 20 + (wl ^ shift)] = act[j];
  }
  __syncthreads();

  // Coalesced writeout: 256 rows x 16 floats; de-swizzle per (p, tid):
  // s = r>>5, float4 base = w0 ^ (s&4), component permute j ^ (s&3).
  float* ob = out + (size_t)bv * 1048576 + h * 64 + W0;
#pragma unroll
  for (int p = 0; p < 4; ++p) {
    int r  = p * 64 + (tid >> 2);
    int w0 = (tid & 3) * 4;
    int s  = r >> 5;
    float4 tv = *(const float4*)(so + r * 20 + (w0 ^ (s & 4)));
    float tt[4] = {tv.x, tv.y, tv.z, tv.w};
    const int pm = s & 3;
    float4 u = make_float4(tt[0 ^ pm], tt[1 ^ pm], tt[2 ^ pm], tt[3 ^ pm]);
    *(float4*)(ob + (size_t)r * 4096 + w0) = u;
  }
}

extern "C" void kernel_launch(void* const* d_in, const int* in_sizes, int n_in,
                              void* d_out, int out_size, void* d_ws, size_t ws_size,
                              hipStream_t stream) {
  const float* x  = (const float*)d_in[0];
  const float* W  = (const float*)d_in[1];
  const float* b  = (const float*)d_in[2];
  float* out = (float*)d_out;

  _Float16* th    = (_Float16*)d_ws;            // 2,097,152 halves (4 MB)
  _Float16* Wp    = th + 2097152;               // 106,496 halves (208 KB)
  _Float16* votes = Wp + 106496;                // 33,554,432 halves (64 MB)

  k_pack2<<<256, 256, 0, stream>>>(x, th);
  k_packw<<<416, 256, 0, stream>>>(W, Wp);
  k_conv<<<2048, 512, 0, stream>>>(th, Wp, votes);
  k_routing4<<<2048, 256, 0, stream>>>(votes, b, out);
}

// Round 6
// 131.138 us; speedup vs baseline: 1.1216x; 1.0360x over previous
//
#include <hip/hip_runtime.h>
#include <hip/hip_bf16.h>

// Shapes: x(8,16,4,64,64) f32, W(256,16,5,5) f32, b(1,1,8,32) f32
// out(8,32,8,64,64) f32.
//
// Reference reshapes (verified passing R1/R2/R4):
//   conv input  t2[n,a,h,w] = x[b0, fl&15, ci, fl>>10, (fl>>4)&63],
//     fl = a*4096 + h*64 + w, n = ci*8 + b0
//   votes flat (n,oc,y,x) reinterpreted by routing as (bv,civ,h,w,o,ao)
//     with n = bv*4 + civ.
// Conv = implicit GEMM on v_mfma_f32_16x16x32_f16 (measured layouts m89/m120).
//
// LEDGER (do not re-try): removing the softmax max-subtract in routing FAILS
// deterministically (R3+R5, identical absmax 0.78515625) despite the overflow
// analysis saying it is safe. Max-subtract is permanently restored.

typedef _Float16 half8 __attribute__((ext_vector_type(8)));
typedef _Float16 half4v __attribute__((ext_vector_type(4)));
typedef float floatx4 __attribute__((ext_vector_type(4)));

#define EPSF 1e-7f

// ---------- cross-lane reductions at VALU rate (no ds_bpermute/swizzle) ----------
template <int CTRL>
__device__ __forceinline__ float dppmov(float x) {
  return __int_as_float(__builtin_amdgcn_update_dpp(
      0, __float_as_int(x), CTRL, 0xf, 0xf, false));
}
// reduce-add over lane bits 0..2 (atoms): ^1, ^2, then ^7 half-mirror completes 8-group.
__device__ __forceinline__ float red_a_add(float x) {
  x += dppmov<0xB1>(x);   // quad_perm [1,0,3,2] : ^1
  x += dppmov<0x4E>(x);   // quad_perm [2,3,0,1] : ^2
  x += dppmov<0x141>(x);  // row_half_mirror     : ^7
  return x;
}
// reduce over lane bits 3..5 (capsule o): ^8 = row_ror:8, ^16/^32 = permlane swaps.
__device__ __forceinline__ float red_o_add(float x) {
  x += dppmov<0x128>(x);  // row_ror:8 == ^8
  { float a = x, b = x;
    asm("v_permlane16_swap_b32 %0, %1" : "+v"(a), "+v"(b));
    x = a + b; }
  { float a = x, b = x;
    asm("v_permlane32_swap_b32 %0, %1" : "+v"(a), "+v"(b));
    x = a + b; }
  return x;
}
__device__ __forceinline__ float red_o_max(float x) {
  x = fmaxf(x, dppmov<0x128>(x));
  { float a = x, b = x;
    asm("v_permlane16_swap_b32 %0, %1" : "+v"(a), "+v"(b));
    x = fmaxf(a, b); }
  { float a = x, b = x;
    asm("v_permlane32_swap_b32 %0, %1" : "+v"(a), "+v"(b));
    x = fmaxf(a, b); }
  return x;
}

// LDS-tile transpose pack: x -> th (n, a0h, h, w, 8a) f16.  (unchanged)
__global__ __launch_bounds__(256) void k_pack2(const float* __restrict__ x,
                                               _Float16* __restrict__ th) {
  __shared__ float lin[32 * 306 + 18];
  const int bid = blockIdx.x;            // 256 blocks
  const int n   = bid >> 3;
  const int a0h = (bid >> 2) & 1;
  const int W0  = (bid & 3) * 16;
  const int ci = n >> 3, b0 = n & 7;
  const int tid = threadIdx.x;
  const float* xb = x + b0 * 262144 + ci * 4096 + W0;

  for (int p = 0; p < 8; ++p) {
    int rr = p * 64 + (tid >> 2);
    int q  = (tid & 3) * 4;
    int a1 = rr >> 5, m = rr & 31;
    float4 v = *(const float4*)(xb + a1 * 16384 + (a0h * 32 + m) * 64 + q);
    float* d = lin + m * 306 + a1 * 18 + q;
    d[0] = v.x; d[1] = v.y; d[2] = v.z; d[3] = v.w;
  }
  __syncthreads();

  _Float16* tb = th + (size_t)n * 65536 + a0h * 32768 + W0 * 128;
  for (int hh = 0; hh < 4; ++hh) {
    int w1 = tid >> 4, a1 = tid & 15;
    half8 v;
#pragma unroll
    for (int j = 0; j < 8; ++j)
      v[j] = (_Float16)lin[(j * 4 + hh) * 306 + a1 * 18 + w1];
    *(half8*)(tb + hh * 8192 + w1 * 128 + a1 * 8) = v;
  }
}

// W (oc,a,ky,kx) f32 -> Wp (kk=0..25, oc, a) f16; plane kk==25 is zeros. (unchanged)
__global__ __launch_bounds__(256) void k_packw(const float* __restrict__ W,
                                               _Float16* __restrict__ Wp) {
  int id = blockIdx.x * 256 + threadIdx.x;      // 106,496 = 26*4096
  int a  = id & 15;
  int oc = (id >> 4) & 255;
  int kk = id >> 12;
  Wp[id] = (kk < 25) ? (_Float16)W[oc * 400 + a * 25 + kk] : (_Float16)0.0f;
}

// Conv v5: R4's passing structure + explicit 2-stage software pipeline:
// step s+1's bf (LDS) and aw (L2) loads are issued before step s's MFMA burst.
// Loads, addresses and accumulation order identical to R4 -> votes bit-identical.
__global__ __launch_bounds__(512) void k_conv(const _Float16* __restrict__ th,
                                              const _Float16* __restrict__ Wp,
                                              _Float16* __restrict__ votes) {
  __shared__ _Float16 lds[16384];   // input tile [0,5440); epilogue reuses 32KB
  const int orig = blockIdx.x;      // 2048
  const int lid  = (orig & 7) * 256 + (orig >> 3);   // bijective (2048 % 8 == 0)
  const int y = lid & 63;
  const int n = lid >> 6;
  const int tid = threadIdx.x;

  for (int c = tid; c < 680; c += 512) {
    int a0h = c / 340;
    int rem = c - a0h * 340;
    int r   = rem / 68;
    int col = rem - r * 68;
    int row = y + r - 2;
    half8 v = {};
    if (col >= 2 && col <= 65 && row >= 0 && row < 64)
      v = *(const half8*)(th + (size_t)(((n * 2 + a0h) * 64 + row) * 64 + (col - 2)) * 8);
    *(half8*)(lds + c * 8) = v;
  }
  __syncthreads();

  const int lane  = tid & 63;
  const int wv    = tid >> 6;       // 0..7
  const int col16 = lane & 15;
  const int quad  = lane >> 4;      // 0..3
  const int t     = quad >> 1;      // tap-within-pair
  const int a0h   = quad & 1;       // atom-half
  const int m0    = wv * 32;

  floatx4 acc[2][4] = {};

  const _Float16* wbase = Wp + (size_t)t * 4096 + (m0 + col16) * 16 + a0h * 8;
  const _Float16* lbase = lds + (a0h * 340 + col16) * 8;

  half8 bfc[4], awc[2], bfn[4], awn[2];
  {
    // s = 0 taps: k0=0 -> e0=0, k1=1 -> e1=1
    const _Float16* lb = lbase + (t ? 1 : 0) * 8;
#pragma unroll
    for (int xt = 0; xt < 4; ++xt)
      bfc[xt] = *(const half8*)(lb + xt * 128);
#pragma unroll
    for (int oct = 0; oct < 2; ++oct)
      awc[oct] = *(const half8*)(wbase + oct * 256);
  }

#pragma unroll
  for (int s = 0; s < 13; ++s) {
    if (s < 12) {
      const int k0 = 2 * (s + 1);
      const int k1 = (2 * (s + 1) + 1 > 24) ? 24 : 2 * (s + 1) + 1;
      const int e0 = (k0 / 5) * 68 + (k0 % 5);
      const int e1 = (k1 / 5) * 68 + (k1 % 5);
      const _Float16* lb = lbase + (t ? e1 : e0) * 8;
#pragma unroll
      for (int xt = 0; xt < 4; ++xt)
        bfn[xt] = *(const half8*)(lb + xt * 128);
#pragma unroll
      for (int oct = 0; oct < 2; ++oct)
        awn[oct] = *(const half8*)(wbase + (size_t)(s + 1) * 8192 + oct * 256);
    }
#pragma unroll
    for (int oct = 0; oct < 2; ++oct)
#pragma unroll
      for (int xt = 0; xt < 4; ++xt)
        acc[oct][xt] = __builtin_amdgcn_mfma_f32_16x16x32_f16(
            awc[oct], bfc[xt], acc[oct][xt], 0, 0, 0);
    if (s < 12) {
#pragma unroll
      for (int xt = 0; xt < 4; ++xt) bfc[xt] = bfn[xt];
#pragma unroll
      for (int oct = 0; oct < 2; ++oct) awc[oct] = awn[oct];
    }
  }

  // ---- epilogue: R4's exact staged writeout (swizzle sw=(oc&15)>>1) ----
  __syncthreads();
#pragma unroll
  for (int oct = 0; oct < 2; ++oct)
#pragma unroll
    for (int xt = 0; xt < 4; ++xt)
#pragma unroll
      for (int r = 0; r < 4; ++r) {
        int oc = m0 + oct * 16 + quad * 4 + r;
        int xx = xt * 16 + col16;
        int sw = (oc & 15) >> 1;
        lds[oc * 64 + (xx ^ (sw << 3))] = (_Float16)acc[oct][xt][r];
      }
  __syncthreads();
  _Float16* vb2 = votes + (size_t)n * 1048576 + y * 64;
#pragma unroll
  for (int it = 0; it < 4; ++it) {
    int idx = it * 512 + tid;          // 2048 half8 chunks
    int oc  = idx >> 3;
    int x0  = (idx & 7) << 3;
    int sw  = (oc & 15) >> 1;
    half8 hv = *(const half8*)(lds + oc * 64 + (x0 ^ (sw << 3)));
    *(half8*)(vb2 + (size_t)oc * 4096 + x0) = hv;
  }
}

// Routing v4: EXACT R2/R4-passing version (max-subtract present — see LEDGER).
__global__ __launch_bounds__(256) void k_routing4(
    const _Float16* __restrict__ votes, const float* __restrict__ bias,
    float* __restrict__ out) {
  __shared__ float so[256 * 20];        // 20 KB
  const int tid  = threadIdx.x;
  const int lane = tid & 63;
  const int wv   = tid >> 6;
  const int bid  = blockIdx.x;          // 2048
  const int bv = bid >> 8;
  const int h  = (bid >> 2) & 63;
  const int W0 = (bid & 3) * 16;

  float4 bia = *(const float4*)(bias + lane * 4);
  const int o     = lane >> 3;
  const int a0    = (lane & 7) * 4;
  const int shift = a0 >> 2;            // so[] column swizzle for this lane's rows
  float bb[4] = {bia.x, bia.y, bia.z, bia.w};

  for (int k = 0; k < 4; ++k) {
    const int wl = wv * 4 + k;          // 0..15
    const int w  = W0 + wl;
    const _Float16* vb = votes + (size_t)bv * 4194304 + h * 16384 + w * 256 + lane * 4;
    float v[4][4];
#pragma unroll
    for (int i = 0; i < 4; ++i) {
      half4v hv = *(const half4v*)(vb + (size_t)i * 1048576);
#pragma unroll
      for (int j = 0; j < 4; ++j) v[i][j] = (float)hv[j];
    }

    float logit[4], act[4], pr[4];

    // ---- round 0: logits==0 -> route==1/8 exactly; skip the softmax ----
#pragma unroll
    for (int j = 0; j < 4; ++j)
      pr[j] = fmaf(0.125f, (v[0][j] + v[1][j]) + (v[2][j] + v[3][j]), bb[j]);
    {
      float sq = pr[0]*pr[0] + pr[1]*pr[1] + pr[2]*pr[2] + pr[3]*pr[3];
      sq = red_a_add(sq);
      float sc = sq * __builtin_amdgcn_rcpf(1.f + sq)
                    * __builtin_amdgcn_rsqf(sq + EPSF);
#pragma unroll
      for (int j = 0; j < 4; ++j) act[j] = pr[j] * sc;
    }
#pragma unroll
    for (int i = 0; i < 4; ++i) {
      float ag = v[i][0]*act[0] + v[i][1]*act[1] + v[i][2]*act[2] + v[i][3]*act[3];
      logit[i] = red_a_add(ag);
    }

    // ---- rounds 1,2 ----
#pragma unroll
    for (int r = 1; r < 3; ++r) {
      float route[4];
#pragma unroll
      for (int i = 0; i < 4; ++i) {
        float m = red_o_max(logit[i]);
        float e = __expf(logit[i] - m);
        float s = red_o_add(e);
        route[i] = e * __builtin_amdgcn_rcpf(s);
      }
#pragma unroll
      for (int j = 0; j < 4; ++j) pr[j] = bb[j];
#pragma unroll
      for (int i = 0; i < 4; ++i)
#pragma unroll
        for (int j = 0; j < 4; ++j)
          pr[j] = fmaf(route[i], v[i][j], pr[j]);
      float sq = pr[0]*pr[0] + pr[1]*pr[1] + pr[2]*pr[2] + pr[3]*pr[3];
      sq = red_a_add(sq);
      float sc = sq * __builtin_amdgcn_rcpf(1.f + sq)
                    * __builtin_amdgcn_rsqf(sq + EPSF);
#pragma unroll
      for (int j = 0; j < 4; ++j) act[j] = pr[j] * sc;
      if (r < 2) {
#pragma unroll
        for (int i = 0; i < 4; ++i) {
          float ag = v[i][0]*act[0] + v[i][1]*act[1] + v[i][2]*act[2] + v[i][3]*act[3];
          logit[i] += red_a_add(ag);
        }
      }
    }

    // stage: row = (a0+j)*8 + o, col = wl ^ (row>>5)  (row>>5 == a0>>2)
#pragma unroll
    for (int j = 0; j < 4; ++j)
      so[((a0 + j) * 8 + o) * 20 + (wl ^ shift)] = act[j];
  }
  __syncthreads();

  // Coalesced writeout: 256 rows x 16 floats; de-swizzle per (p, tid):
  // s = r>>5, float4 base = w0 ^ (s&4), component permute j ^ (s&3).
  float* ob = out + (size_t)bv * 1048576 + h * 64 + W0;
#pragma unroll
  for (int p = 0; p < 4; ++p) {
    int r  = p * 64 + (tid >> 2);
    int w0 = (tid & 3) * 4;
    int s  = r >> 5;
    float4 tv = *(const float4*)(so + r * 20 + (w0 ^ (s & 4)));
    float tt[4] = {tv.x, tv.y, tv.z, tv.w};
    const int pm = s & 3;
    float4 u = make_float4(tt[0 ^ pm], tt[1 ^ pm], tt[2 ^ pm], tt[3 ^ pm]);
    *(float4*)(ob + (size_t)r * 4096 + w0) = u;
  }
}

extern "C" void kernel_launch(void* const* d_in, const int* in_sizes, int n_in,
                              void* d_out, int out_size, void* d_ws, size_t ws_size,
                              hipStream_t stream) {
  const float* x  = (const float*)d_in[0];
  const float* W  = (const float*)d_in[1];
  const float* b  = (const float*)d_in[2];
  float* out = (float*)d_out;

  _Float16* th    = (_Float16*)d_ws;            // 2,097,152 halves (4 MB)
  _Float16* Wp    = th + 2097152;               // 106,496 halves (208 KB)
  _Float16* votes = Wp + 106496;                // 33,554,432 halves (64 MB)

  k_pack2<<<256, 256, 0, stream>>>(x, th);
  k_packw<<<416, 256, 0, stream>>>(W, Wp);
  k_conv<<<2048, 512, 0, stream>>>(th, Wp, votes);
  k_routing4<<<2048, 256, 0, stream>>>(votes, b, out);
}